// Round 9
// baseline (118.142 us; speedup 1.0000x reference)
//
#include <hip/hip_runtime.h>
#include <hip/hip_fp16.h>

// N=1536 T=20 H=64 E=16 M=128
// pre1[i,j] = Q[j] - P[i];  out[i] = max_j relu( relu(Q[j]-P[i]) @ W2 + b2 )
//
// R9 hybrid (from R4-R8 evidence):
//  - R4-R7 were global-latency-bound (B in regs, Q loads uncovered).
//  - R8 was LDS-BW-bound: re-reading W2T from LDS = 16/20 ds_read_b128 per
//    tile -> 1.5GB LDS traffic ~ 22us of LDS pipe, >= MFMA demand.
//  - R9: B (W2T) in REGISTERS (LDS pipe drops to 4 ds_read/tile/wave);
//    Q staged via global_load_lds ping-pong (global latency hidden);
//    NI=2 -> live set ~ bfrag64+pv32+acc32+misc ~150 <= 168 -> 3 waves/SIMD;
//    3 waves x 32 MFMA/tile (~590cy) vs ~230cy VALU+LDS -> MFMA pipe ~75%.
//  - JSPLIT=4: 768 blocks = exactly 3 blocks/CU, one generation, no tail.
//  - Q keeps 16B-granule XOR swizzle (conflict-free b128); W2T plain.

#define NN 1536
#define HH 64
#define EE 16
#define MM 128
#define TT 20
#define NI 2                 // i's per wave
#define IB 8                 // i's per block (4 waves * NI)
#define JSPLIT 4
#define NIGRP (NN / IB)      // 192 i-groups
#define NTILE (96 / JSPLIT)  // 24 j-tiles of 16 per block

typedef _Float16 half8 __attribute__((ext_vector_type(8)));
typedef float f32x4 __attribute__((ext_vector_type(4)));

__device__ __forceinline__ void async16(const void* g, void* l) {
  __builtin_amdgcn_global_load_lds(
      (const __attribute__((address_space(1))) unsigned int*)g,
      (__attribute__((address_space(3))) unsigned int*)l, 16, 0, 0);
}

// grid NN, block 128. Qs (swizzled), P (plain), W2T (plain) fp16; out zeroed.
// Swizzle: within a 256B row, 16B-granule gm stored at position gm ^ (row&15).
__global__ __launch_bounds__(128) void precompute_kernel(
    const float* __restrict__ hidden, const float* __restrict__ gt,
    const float* __restrict__ We, const float* __restrict__ be,
    const float* __restrict__ W1, const float* __restrict__ b1,
    const float* __restrict__ W2,
    _Float16* __restrict__ Qs, _Float16* __restrict__ P,
    _Float16* __restrict__ W2T, float* __restrict__ out)
{
  const int j = blockIdx.x;
  const int m = threadIdx.x;
  const float* hrow = hidden + j * HH;
  float a = 0.f;
  #pragma unroll 8
  for (int h = 0; h < HH; ++h) a = fmaf(hrow[h], W1[h * MM + m], a);
  float ve0 = 0.f, ve1 = 0.f, cm = b1[m];
  #pragma unroll
  for (int e = 0; e < EE; ++e) {
    float w1e = W1[(HH + e) * MM + m];
    ve0 = fmaf(We[e], w1e, ve0);       // We[0][e]
    ve1 = fmaf(We[EE + e], w1e, ve1);  // We[1][e]
    cm  = fmaf(be[e], w1e, cm);
  }
  const float e0 = gt[j * (2 * TT) + 2 * (TT - 1)];
  const float e1 = gt[j * (2 * TT) + 2 * (TT - 1) + 1];
  const float p = fmaf(e0, ve0, e1 * ve1);
  P[j * MM + m] = (_Float16)p;
  const int swz = ((((m >> 3) ^ (j & 15)) << 3) | (m & 7));
  Qs[j * MM + swz] = (_Float16)(a + p + cm);
  if (j < HH) W2T[j * MM + m] = (_Float16)W2[m * HH + j];  // W2T[col][k] plain
  if (m < HH) out[j * HH + m] = 0.f;
}

// grid NIGRP*JSPLIT (=768), block 256 (4 waves). Wave w: i = ig*8 + w*2 + {0,1}.
// No min-waves arg (R2 lesson); est. live ~150 regs -> 3 waves/SIMD naturally.
__global__ __launch_bounds__(256) void pairmlp_max_kernel(
    const _Float16* __restrict__ Qs, const _Float16* __restrict__ P,
    const _Float16* __restrict__ W2T, const float* __restrict__ b2,
    float* __restrict__ out)
{
  __shared__ __align__(16) _Float16 sQ[2][16 * MM];    // 2 x 4KB tiles, swizzled

  const int tid  = threadIdx.x;
  const int wave = tid >> 6;
  const int lane = tid & 63;
  const int quad = lane >> 4;
  const int lcol = lane & 15;
  const int ig = blockIdx.x % NIGRP;
  const int js = blockIdx.x / NIGRP;
  const int i0 = ig * IB + wave * NI;
  const int jt0 = js * NTILE;

  // stage tile 0 (4KB contiguous; pattern = wave-uniform base + lane*16)
  async16((const char*)Qs + (size_t)jt0 * 4096 + tid * 16, (char*)sQ[0] + tid * 16);

  // B fragments in registers: bfrag[ct][ks] = W2T[ct*16+lcol][ks*32+quad*8 ..+8]
  half8 bfrag[4][4];
  #pragma unroll
  for (int ct = 0; ct < 4; ++ct) {
    const _Float16* wrow = W2T + (ct * 16 + lcol) * MM + quad * 8;
    #pragma unroll
    for (int ks = 0; ks < 4; ++ks)
      bfrag[ct][ks] = *(const half8*)(wrow + ks * 32);
  }

  // P fragments (plain layout)
  half8 pv[NI][4];
  #pragma unroll
  for (int ii = 0; ii < NI; ++ii) {
    const _Float16* prow = P + (i0 + ii) * MM + quad * 8;
    #pragma unroll
    for (int ks = 0; ks < 4; ++ks)
      pv[ii][ks] = *(const half8*)(prow + ks * 32);
  }

  // swizzled per-lane LDS element offsets (Q row = lcol, granule g = ks*4+quad)
  int soff[4];
  #pragma unroll
  for (int ks = 0; ks < 4; ++ks)
    soff[ks] = lcol * MM + ((((ks * 4 + quad) ^ lcol) & 15) << 3);

  float rmax[NI][4];
  #pragma unroll
  for (int ii = 0; ii < NI; ++ii)
    #pragma unroll
    for (int ct = 0; ct < 4; ++ct) rmax[ii][ct] = -1e30f;

  const half8 hz = 0;
  const f32x4 zc = {0.f, 0.f, 0.f, 0.f};

  __syncthreads();  // tile0 staged (barrier drains vmcnt)

  #pragma unroll 2
  for (int t = 0; t < NTILE; ++t) {
    // stage tile t+1 into the other buffer (last iter: harmless restage of jt0)
    const int jn = (t + 1 < NTILE) ? (jt0 + t + 1) : jt0;
    async16((const char*)Qs + (size_t)jn * 4096 + tid * 16, (char*)sQ[(t + 1) & 1] + tid * 16);

    const _Float16* qb = sQ[t & 1];
    f32x4 acc[NI][4];
    #pragma unroll
    for (int ks = 0; ks < 4; ++ks) {
      const half8 qg = *(const half8*)(qb + soff[ks]);
      #pragma unroll
      for (int ii = 0; ii < NI; ++ii) {
        half8 s = qg - pv[ii][ks];
        s = __builtin_elementwise_max(s, hz);   // v_pk_sub_f16 + v_pk_max_f16
        if (ks == 0) {
          #pragma unroll
          for (int ct = 0; ct < 4; ++ct)
            acc[ii][ct] = __builtin_amdgcn_mfma_f32_16x16x32_f16(s, bfrag[ct][0], zc, 0, 0, 0);
        } else {
          #pragma unroll
          for (int ct = 0; ct < 4; ++ct)
            acc[ii][ct] = __builtin_amdgcn_mfma_f32_16x16x32_f16(s, bfrag[ct][ks], acc[ii][ct], 0, 0, 0);
        }
      }
    }

    // C/D: col=lcol(+ct*16), row(j)=quad*4+reg
    #pragma unroll
    for (int ii = 0; ii < NI; ++ii)
      #pragma unroll
      for (int ct = 0; ct < 4; ++ct) {
        const float m01 = fmaxf(acc[ii][ct][0], acc[ii][ct][1]);
        const float m23 = fmaxf(acc[ii][ct][2], acc[ii][ct][3]);
        rmax[ii][ct] = fmaxf(rmax[ii][ct], fmaxf(m01, m23));
      }

    // one barrier per tile: staging of t+1 complete AND buf(t) free for t+2
    __syncthreads();
  }

  // combine quad-groups (different j rows), then b2 + relu + atomic max
  #pragma unroll
  for (int ii = 0; ii < NI; ++ii)
    #pragma unroll
    for (int ct = 0; ct < 4; ++ct) {
      float v = rmax[ii][ct];
      v = fmaxf(v, __shfl_xor(v, 16, 64));
      v = fmaxf(v, __shfl_xor(v, 32, 64));
      v = fmaxf(v + b2[ct * 16 + lcol], 0.f);
      if (quad == 0)
        atomicMax((unsigned*)(out + (i0 + ii) * HH + ct * 16 + lcol), __float_as_uint(v));
    }
}

extern "C" void kernel_launch(void* const* d_in, const int* in_sizes, int n_in,
                              void* d_out, int out_size, void* d_ws, size_t ws_size,
                              hipStream_t stream) {
  const float* hidden = (const float*)d_in[0];
  const float* gt     = (const float*)d_in[1];
  const float* We     = (const float*)d_in[2];
  const float* be     = (const float*)d_in[3];
  const float* W1     = (const float*)d_in[4];
  const float* b1     = (const float*)d_in[5];
  const float* W2     = (const float*)d_in[6];
  const float* b2     = (const float*)d_in[7];
  float* out = (float*)d_out;

  _Float16* Qs  = (_Float16*)d_ws;    // NN*MM fp16 swizzled (384KB)
  _Float16* Ph  = Qs + NN * MM;       // NN*MM fp16 plain    (384KB)
  _Float16* W2T = Ph + NN * MM;       // HH*MM fp16 plain    (16KB)

  precompute_kernel<<<NN, 128, 0, stream>>>(hidden, gt, We, be, W1, b1, W2, Qs, Ph, W2T, out);
  pairmlp_max_kernel<<<NIGRP * JSPLIT, 256, 0, stream>>>(Qs, Ph, W2T, b2, out);
}